// Round 9
// baseline (645.816 us; speedup 1.0000x reference)
//
#include <hip/hip_runtime.h>
#include <math.h>

#define NB 2
#define NC 96
#define ND 8
#define NHH 64
#define NWW 64
#define NN 32768          // ND*NHH*NWW
#define NTOK 8
#define NHEADS 6
#define GSZ 128
#define NGRP 256          // NN/GSZ
#define NMLP 192

typedef float4 f4;

__device__ __forceinline__ float gelu_f(float x) {
    return 0.5f * x * (1.0f + erff(x * 0.70710678118654752440f));
}

// ---------------------------------------------------------------------------
// Precompute (grid=5): blk0: normalized means, gdot/bdot, kg/vg.
// blk1..4: wpc = Wproj @ Wconv, 24 rows each, fully LDS-staged.
// ---------------------------------------------------------------------------
__global__ void __launch_bounds__(256) k_precompute(
    const float* __restrict__ means, const float* __restrict__ g1, const float* __restrict__ b1v,
    const float* __restrict__ Wkg, const float* __restrict__ Wvg,
    const float* __restrict__ Wproj, const float* __restrict__ Wconv,
    float* __restrict__ mnn, float* __restrict__ gdot, float* __restrict__ bdot,
    float* __restrict__ kg, float* __restrict__ vg, float* __restrict__ wpc) {
    int blk = blockIdx.x; int tid = threadIdx.x;
    if (blk == 0) {
        __shared__ float mlds[NTOK*NC];
        __shared__ float glds[NC], blds[NC];
        for (int i = tid; i < NTOK*NC; i += 256) mlds[i] = means[i];
        if (tid < NC) { glds[tid] = g1[tid]; blds[tid] = b1v[tid]; }
        __syncthreads();
        if (tid < NTOK) {
            float ss = 0.f;
            for (int c = 0; c < NC; ++c) { float v = mlds[tid*NC+c]; ss += v*v; }
            float inv = 1.0f / fmaxf(sqrtf(ss), 1e-12f);
            float gd = 0.f, bd = 0.f;
            for (int c = 0; c < NC; ++c) {
                float v = mlds[tid*NC+c] * inv;
                mnn[tid*NC+c] = v;
                gd += glds[c]*v; bd += blds[c]*v;
            }
            gdot[tid] = gd; bdot[tid] = bd;
        }
        // kg/vg: layout [h][t][e], e<16
        for (int i = tid; i < NHEADS*NTOK*16; i += 256) {
            int h = i / (NTOK*16); int r = i % (NTOK*16); int t = r / 16; int e = r % 16;
            float sk = 0.f, sv = 0.f;
            for (int c = 0; c < NC; ++c) {
                float mv = mlds[t*NC+c];
                sk += mv * Wkg[c*NC + h*16+e];
                sv += mv * Wvg[c*NC + h*16+e];
            }
            kg[i] = sk; vg[i] = sv;
        }
    } else {
        int r0 = (blk-1)*24;
        __shared__ float wcv[NC][NC];
        __shared__ float wpl[24][NC];
        for (int i = tid; i < NC*NC; i += 256) wcv[i/NC][i%NC] = Wconv[i];
        for (int i = tid; i < 24*NC; i += 256) wpl[i/NC][i%NC] = Wproj[(r0 + i/NC)*NC + i%NC];
        __syncthreads();
        for (int o = tid; o < 24*NC; o += 256) {
            int r = o / NC, c = o % NC;
            float s = 0.f;
            for (int k = 0; k < NC; ++k) s += wpl[r][k]*wcv[k][c];
            wpc[(r0+r)*NC + c] = s;
        }
    }
}

// ---------------------------------------------------------------------------
// LN1 (reads x in (b,c,n), writes xn in (b,n,c)) fused with cluster argmax.
// ---------------------------------------------------------------------------
__global__ void __launch_bounds__(256) k_ln1(
    const float* __restrict__ x, const float* __restrict__ g1, const float* __restrict__ b1v,
    const float* __restrict__ mnn, const float* __restrict__ gdot, const float* __restrict__ bdot,
    float* __restrict__ xn, int* __restrict__ belong) {
    __shared__ __align__(16) float xt[NC][68];
    __shared__ float meanl[64], rstdl[64];
    __shared__ float gl[NC], bl[NC], gdl[NTOK], bdl[NTOK];
    int b = blockIdx.y; int n0 = blockIdx.x * 64;
    int tid = threadIdx.x;
    if (tid < NC) { gl[tid] = g1[tid]; bl[tid] = b1v[tid]; }
    if (tid >= NC && tid < NC+NTOK) { gdl[tid-NC] = gdot[tid-NC]; bdl[tid-NC] = bdot[tid-NC]; }
    for (int i = tid; i < NC*64; i += 256) {
        int c = i >> 6, n = i & 63;
        xt[c][n] = x[((size_t)b*NC + c)*NN + n0 + n];
    }
    __syncthreads();
    int lane = tid & 63, w = tid >> 6;
    float ga = gl[lane];
    float gb = (lane < 32) ? gl[64+lane] : 0.f;
    float ma[NTOK], mb[NTOK];
#pragma unroll
    for (int t = 0; t < NTOK; ++t) {
        ma[t] = mnn[t*NC + lane];
        mb[t] = (lane < 32) ? mnn[t*NC + 64 + lane] : 0.f;
    }
    for (int tk = 0; tk < 16; ++tk) {
        int tok = w*16 + tk;
        float a  = xt[lane][tok];
        float bb = (lane < 32) ? xt[64+lane][tok] : 0.f;
        float red[10];
        red[0] = a + bb;
        red[1] = a*a + bb*bb;
        float ag = a*ga, bg = bb*gb;
#pragma unroll
        for (int t = 0; t < NTOK; ++t) red[2+t] = ag*ma[t] + bg*mb[t];
#pragma unroll
        for (int off = 32; off > 0; off >>= 1) {
#pragma unroll
            for (int r = 0; r < 10; ++r) red[r] += __shfl_xor(red[r], off);
        }
        if (lane == 0) {
            float mean = red[0] * (1.0f/NC);
            float var  = red[1] * (1.0f/NC) - mean*mean;
            float rstd = rsqrtf(var + 1e-5f);
            meanl[tok] = mean; rstdl[tok] = rstd;
            int best = 0; float bestv = -1e30f;
#pragma unroll
            for (int t = 0; t < NTOK; ++t) {
                float sc = rstd*(red[2+t] - mean*gdl[t]) + bdl[t];
                if (sc > bestv) { bestv = sc; best = t; }
            }
            belong[b*NN + n0 + tok] = best;
        }
    }
    __syncthreads();
    for (int i = tid; i < 64*NC; i += 256) {
        int n = i / NC, c = i % NC;
        float v = (xt[c][n] - meanl[n]) * rstdl[n] * gl[c] + bl[c];
        xn[((size_t)b*NN + n0 + n)*NC + c] = v;
    }
}

// ---------------------------------------------------------------------------
// Stable counting sort of `belong` (values 0..7): hist -> scan -> scatter
// ---------------------------------------------------------------------------
__global__ void __launch_bounds__(256) k_hist(const int* __restrict__ belong, int* __restrict__ hist) {
    int b = blockIdx.y, ch = blockIdx.x, tid = threadIdx.x;
    __shared__ int wc[4][NTOK];
    int myt = belong[b*NN + ch*256 + tid];
    int w = tid >> 6, lane = tid & 63;
#pragma unroll
    for (int t = 0; t < NTOK; ++t) {
        unsigned long long m = __ballot(myt == t);
        if (lane == 0) wc[w][t] = __popcll(m);
    }
    __syncthreads();
    if (tid < NTOK) hist[(b*128 + ch)*NTOK + tid] = wc[0][tid]+wc[1][tid]+wc[2][tid]+wc[3][tid];
}

__global__ void __launch_bounds__(256) k_scan(const int* __restrict__ hist, int* __restrict__ base) {
    int b = blockIdx.x, tid = threadIdx.x;
    __shared__ int A[NTOK][128], Bf[NTOK][128], orig[NTOK][128];
    __shared__ int cb[NTOK];
    for (int i = tid; i < NTOK*128; i += 256) {
        int t = i >> 7, ch = i & 127;
        int v = hist[(b*128 + ch)*NTOK + t];
        A[t][ch] = v; orig[t][ch] = v;
    }
    __syncthreads();
    for (int d = 1; d < 128; d <<= 1) {
        for (int i = tid; i < NTOK*128; i += 256) {
            int t = i >> 7, ch = i & 127;
            Bf[t][ch] = A[t][ch] + ((ch >= d) ? A[t][ch-d] : 0);
        }
        __syncthreads();
        for (int i = tid; i < NTOK*128; i += 256) {
            int t = i >> 7, ch = i & 127;
            A[t][ch] = Bf[t][ch];
        }
        __syncthreads();
    }
    if (tid == 0) {
        int run = 0;
        for (int t = 0; t < NTOK; ++t) { cb[t] = run; run += A[t][127]; }
    }
    __syncthreads();
    for (int i = tid; i < NTOK*128; i += 256) {
        int t = i >> 7, ch = i & 127;
        base[(b*128 + ch)*NTOK + t] = cb[t] + A[t][ch] - orig[t][ch];
    }
}

__global__ void __launch_bounds__(256) k_scatteridx(
    const int* __restrict__ belong, const int* __restrict__ base,
    int* __restrict__ idx, int* __restrict__ inv) {
    int b = blockIdx.y, ch = blockIdx.x, tid = threadIdx.x;
    __shared__ int wc[4][NTOK];
    __shared__ int woff[4][NTOK];
    int n = ch*256 + tid;
    int myt = belong[b*NN + n];
    int w = tid >> 6, lane = tid & 63;
    unsigned long long mymask = 0;
#pragma unroll
    for (int t = 0; t < NTOK; ++t) {
        unsigned long long m = __ballot(myt == t);
        if (myt == t) mymask = m;
        if (lane == 0) wc[w][t] = __popcll(m);
    }
    __syncthreads();
    if (tid < 32) {
        int w2 = tid >> 3, t = tid & 7;
        int s = 0;
        for (int ww = 0; ww < w2; ++ww) s += wc[ww][t];
        woff[w2][t] = s;
    }
    __syncthreads();
    int rank = __popcll(mymask & ((1ull << lane) - 1ull));
    int p = base[(b*128+ch)*NTOK + myt] + woff[w][myt] + rank;
    idx[b*NN + p] = n;
    inv[b*NN + n] = p;
}

// ---------------------------------------------------------------------------
// q/k/v = gather(xn, idx) @ {Wq,Wk,Wv}; 128-row tile, thread = 8n x 6c
// ---------------------------------------------------------------------------
__global__ void __launch_bounds__(256) k_qkv(
    const float* __restrict__ xn, const int* __restrict__ idx,
    const float* __restrict__ Wq, const float* __restrict__ Wk, const float* __restrict__ Wv,
    float* __restrict__ qs, float* __restrict__ ks, float* __restrict__ vs) {
    __shared__ __align__(16) float xnT[NC][132];
    __shared__ __align__(16) float wch[32][NC];
    __shared__ int idxl[128];
    int b = blockIdx.y; int p0 = blockIdx.x * 128; int tid = threadIdx.x;
    if (tid < 128) idxl[tid] = idx[b*NN + p0 + tid];
    __syncthreads();
    for (int i = tid; i < 128*NC; i += 256) {
        int p = i / NC, c = i % NC;
        xnT[c][p] = xn[((size_t)b*NN + idxl[p])*NC + c];
    }
    int cx = tid & 15, ny = tid >> 4;   // c = cx*6, n = ny*8
    const float* Ws[3] = {Wq, Wk, Wv};
    float* Os[3] = {qs, ks, vs};
    for (int m = 0; m < 3; ++m) {
        float acc[8][6];
#pragma unroll
        for (int i = 0; i < 8; ++i)
#pragma unroll
            for (int j = 0; j < 6; ++j) acc[i][j] = 0.f;
        const float* W = Ws[m];
        for (int kc = 0; kc < NC; kc += 32) {
            __syncthreads();
            for (int i = tid; i < 32*NC; i += 256) {
                int kk = i / NC, c = i % NC;
                wch[kk][c] = W[(kc+kk)*NC + c];
            }
            __syncthreads();
            for (int kk = 0; kk < 32; ++kk) {
                f4 a0 = *(const f4*)&xnT[kc+kk][ny*8];
                f4 a1 = *(const f4*)&xnT[kc+kk][ny*8+4];
                float a[8] = {a0.x,a0.y,a0.z,a0.w,a1.x,a1.y,a1.z,a1.w};
                float2 w0 = *(const float2*)&wch[kk][cx*6];
                float2 w1 = *(const float2*)&wch[kk][cx*6+2];
                float2 w2 = *(const float2*)&wch[kk][cx*6+4];
                float bb[6] = {w0.x,w0.y,w1.x,w1.y,w2.x,w2.y};
#pragma unroll
                for (int i = 0; i < 8; ++i)
#pragma unroll
                    for (int j = 0; j < 6; ++j) acc[i][j] += a[i]*bb[j];
            }
        }
        float* O = Os[m];
#pragma unroll
        for (int i = 0; i < 8; ++i) {
            size_t off = ((size_t)b*NN + p0 + ny*8 + i)*NC + cx*6;
            float2 s0 = {acc[i][0], acc[i][1]};
            float2 s1 = {acc[i][2], acc[i][3]};
            float2 s2 = {acc[i][4], acc[i][5]};
            *(float2*)&O[off]   = s0;
            *(float2*)&O[off+2] = s1;
            *(float2*)&O[off+4] = s2;
        }
    }
}

// ---------------------------------------------------------------------------
// Windowed attention v3: thread = (row-pair, key-quarter). Each thread
// processes 2 rows x 64 keys, so each K/V ds_read serves 2 rows (halves the
// LDS instruction count, which round-8 counters showed to be the 164 us
// floor: 8 ds_read_b128/key * 128 keys * 48 waves/CU * 8 cyc = 164 us).
// 4 partial softmax states per row merged via shfl_xor(16)+shfl_xor(32).
// Tail: quarters 0/1 do the 8-token global attention for rows r0/r1.
// ---------------------------------------------------------------------------
__global__ void __launch_bounds__(256) k_attn(
    const float* __restrict__ qs, const float* __restrict__ ks, const float* __restrict__ vs,
    const float* __restrict__ kg, const float* __restrict__ vg,
    float* __restrict__ attn) {
    __shared__ __align__(16) f4 kt[256][4];
    __shared__ __align__(16) f4 vt[256][4];
    __shared__ __align__(16) f4 kgs[NTOK][4];
    __shared__ __align__(16) f4 vgs[NTOK][4];
    int g = blockIdx.x, h = blockIdx.y, b = blockIdx.z;
    int tid = threadIdx.x;
    for (int i = tid; i < 1024; i += 256) {
        int r = i >> 2, c = i & 3;
        int src = g*GSZ + r;
        if (g == NGRP-1 && r >= GSZ) src = NN - 1 - (r - GSZ);
        size_t off = ((size_t)b*NN + src)*NC + h*16 + c*4;
        kt[r][c] = *(const f4*)&ks[off];
        vt[r][c] = *(const f4*)&vs[off];
    }
    if (tid < 32) {
        int t = tid >> 2, c = tid & 3;
        kgs[t][c] = *(const f4*)&kg[(h*NTOK + t)*16 + c*4];
        vgs[t][c] = *(const f4*)&vg[(h*NTOK + t)*16 + c*4];
    }
    int wv = tid >> 6, lane = tid & 63;
    int pr = lane & 15;       // row-pair index within wave
    int qt = lane >> 4;       // key quarter 0..3
    int r0 = wv*32 + pr*2;    // rows r0, r0+1
    float qv0[16], qv1[16];
    {
        const f4* qp0 = (const f4*)&qs[((size_t)b*NN + g*GSZ + r0)*NC + h*16];
        const f4* qp1 = (const f4*)&qs[((size_t)b*NN + g*GSZ + r0 + 1)*NC + h*16];
#pragma unroll
        for (int i = 0; i < 4; ++i) {
            f4 t0 = qp0[i], t1 = qp1[i];
            qv0[i*4+0]=t0.x*0.25f; qv0[i*4+1]=t0.y*0.25f; qv0[i*4+2]=t0.z*0.25f; qv0[i*4+3]=t0.w*0.25f;
            qv1[i*4+0]=t1.x*0.25f; qv1[i*4+1]=t1.y*0.25f; qv1[i*4+2]=t1.z*0.25f; qv1[i*4+3]=t1.w*0.25f;
        }
    }
    __syncthreads();
    float m0 = -1e30f, l0 = 0.f, m1 = -1e30f, l1 = 0.f;
    float acc0[16], acc1[16];
#pragma unroll
    for (int e = 0; e < 16; ++e) { acc0[e] = 0.f; acc1[e] = 0.f; }
    int k0 = qt * 64;
    for (int c8 = 0; c8 < 8; ++c8) {
        float s0[8], s1[8];
#pragma unroll
        for (int j = 0; j < 8; ++j) {
            const f4* kp = &kt[k0 + c8*8 + j][0];
            f4 ka = kp[0], kb = kp[1], kc = kp[2], kd = kp[3];
            s0[j] = qv0[0]*ka.x + qv0[1]*ka.y + qv0[2]*ka.z + qv0[3]*ka.w
                  + qv0[4]*kb.x + qv0[5]*kb.y + qv0[6]*kb.z + qv0[7]*kb.w
                  + qv0[8]*kc.x + qv0[9]*kc.y + qv0[10]*kc.z + qv0[11]*kc.w
                  + qv0[12]*kd.x + qv0[13]*kd.y + qv0[14]*kd.z + qv0[15]*kd.w;
            s1[j] = qv1[0]*ka.x + qv1[1]*ka.y + qv1[2]*ka.z + qv1[3]*ka.w
                  + qv1[4]*kb.x + qv1[5]*kb.y + qv1[6]*kb.z + qv1[7]*kb.w
                  + qv1[8]*kc.x + qv1[9]*kc.y + qv1[10]*kc.z + qv1[11]*kc.w
                  + qv1[12]*kd.x + qv1[13]*kd.y + qv1[14]*kd.z + qv1[15]*kd.w;
        }
        float cm0 = fmaxf(fmaxf(fmaxf(s0[0],s0[1]), fmaxf(s0[2],s0[3])),
                          fmaxf(fmaxf(s0[4],s0[5]), fmaxf(s0[6],s0[7])));
        float cm1 = fmaxf(fmaxf(fmaxf(s1[0],s1[1]), fmaxf(s1[2],s1[3])),
                          fmaxf(fmaxf(s1[4],s1[5]), fmaxf(s1[6],s1[7])));
        float nm0 = fmaxf(m0, cm0), nm1 = fmaxf(m1, cm1);
        float corr0 = __expf(m0 - nm0), corr1 = __expf(m1 - nm1);
        m0 = nm0; m1 = nm1;
        l0 *= corr0; l1 *= corr1;
#pragma unroll
        for (int e = 0; e < 16; ++e) { acc0[e] *= corr0; acc1[e] *= corr1; }
#pragma unroll
        for (int j = 0; j < 8; ++j) {
            float p0 = __expf(s0[j] - m0);
            float p1 = __expf(s1[j] - m1);
            l0 += p0; l1 += p1;
            const f4* vp = &vt[k0 + c8*8 + j][0];
            f4 va = vp[0], vb = vp[1], vc = vp[2], vd = vp[3];
            acc0[0] += p0*va.x; acc0[1] += p0*va.y; acc0[2] += p0*va.z; acc0[3] += p0*va.w;
            acc0[4] += p0*vb.x; acc0[5] += p0*vb.y; acc0[6] += p0*vb.z; acc0[7] += p0*vb.w;
            acc0[8] += p0*vc.x; acc0[9] += p0*vc.y; acc0[10] += p0*vc.z; acc0[11] += p0*vc.w;
            acc0[12] += p0*vd.x; acc0[13] += p0*vd.y; acc0[14] += p0*vd.z; acc0[15] += p0*vd.w;
            acc1[0] += p1*va.x; acc1[1] += p1*va.y; acc1[2] += p1*va.z; acc1[3] += p1*va.w;
            acc1[4] += p1*vb.x; acc1[5] += p1*vb.y; acc1[6] += p1*vb.z; acc1[7] += p1*vb.w;
            acc1[8] += p1*vc.x; acc1[9] += p1*vc.y; acc1[10] += p1*vc.z; acc1[11] += p1*vc.w;
            acc1[12] += p1*vd.x; acc1[13] += p1*vd.y; acc1[14] += p1*vd.z; acc1[15] += p1*vd.w;
        }
    }
    // merge 4 quarter-states per row via shfl_xor tree (offsets 16, 32)
#pragma unroll
    for (int off = 16; off <= 32; off <<= 1) {
        float om = __shfl_xor(m0, off), ol = __shfl_xor(l0, off);
        float mw = fmaxf(m0, om);
        float e0 = __expf(m0 - mw), e1 = __expf(om - mw);
        l0 = l0*e0 + ol*e1; m0 = mw;
#pragma unroll
        for (int e = 0; e < 16; ++e) {
            float oa = __shfl_xor(acc0[e], off);
            acc0[e] = acc0[e]*e0 + oa*e1;
        }
        om = __shfl_xor(m1, off); ol = __shfl_xor(l1, off);
        mw = fmaxf(m1, om);
        e0 = __expf(m1 - mw); e1 = __expf(om - mw);
        l1 = l1*e0 + ol*e1; m1 = mw;
#pragma unroll
        for (int e = 0; e < 16; ++e) {
            float oa = __shfl_xor(acc1[e], off);
            acc1[e] = acc1[e]*e0 + oa*e1;
        }
    }
    // select this lane's tail row (qt==0 -> r0, qt==1 -> r0+1) via cndmask
    float qvs[16], accs[16];
#pragma unroll
    for (int e = 0; e < 16; ++e) {
        qvs[e]  = (qt == 1) ? qv1[e]  : qv0[e];
        accs[e] = (qt == 1) ? acc1[e] : acc0[e];
    }
    float ls = (qt == 1) ? l1 : l0;
    if (qt < 2) {
        // global attention over 8 cluster tokens for row r0+qt
        float m2 = -1e30f, l2 = 0.f;
        float a2[16];
#pragma unroll
        for (int e = 0; e < 16; ++e) a2[e] = 0.f;
#pragma unroll
        for (int t = 0; t < NTOK; ++t) {
            f4 ka = kgs[t][0], kb = kgs[t][1], kc = kgs[t][2], kd = kgs[t][3];
            float s = qvs[0]*ka.x + qvs[1]*ka.y + qvs[2]*ka.z + qvs[3]*ka.w
                    + qvs[4]*kb.x + qvs[5]*kb.y + qvs[6]*kb.z + qvs[7]*kb.w
                    + qvs[8]*kc.x + qvs[9]*kc.y + qvs[10]*kc.z + qvs[11]*kc.w
                    + qvs[12]*kd.x + qvs[13]*kd.y + qvs[14]*kd.z + qvs[15]*kd.w;
            float nm2 = fmaxf(m2, s);
            float corr = __expf(m2 - nm2);
            m2 = nm2;
            l2 *= corr;
            float p = __expf(s - m2);
            l2 += p;
            f4 va = vgs[t][0], vb = vgs[t][1], vc = vgs[t][2], vd = vgs[t][3];
#pragma unroll
            for (int e = 0; e < 16; ++e) a2[e] *= corr;
            a2[0] += p*va.x; a2[1] += p*va.y; a2[2] += p*va.z; a2[3] += p*va.w;
            a2[4] += p*vb.x; a2[5] += p*vb.y; a2[6] += p*vb.z; a2[7] += p*vb.w;
            a2[8] += p*vc.x; a2[9] += p*vc.y; a2[10] += p*vc.z; a2[11] += p*vc.w;
            a2[12] += p*vd.x; a2[13] += p*vd.y; a2[14] += p*vd.z; a2[15] += p*vd.w;
        }
        float inv2 = 1.f / l2;
        float invw = 1.f / ls;
        float o[16];
#pragma unroll
        for (int e = 0; e < 16; ++e) o[e] = accs[e]*invw + a2[e]*inv2;
        f4* op = (f4*)&attn[((size_t)b*NN + g*GSZ + r0 + qt)*NC + h*16];
#pragma unroll
        for (int i = 0; i < 4; ++i) {
            f4 t = {o[i*4+0], o[i*4+1], o[i*4+2], o[i*4+3]};
            op[i] = t;
        }
    }
}

// ---------------------------------------------------------------------------
// Scatter back (inv), @ (Wproj@Wconv), + residual x; writes xrt in (b,c,n)
// ---------------------------------------------------------------------------
__global__ void __launch_bounds__(256) k_scatproj(
    const float* __restrict__ attn, const int* __restrict__ inv,
    const float* __restrict__ wpc, const float* __restrict__ x,
    float* __restrict__ xrt) {
    __shared__ __align__(16) float attT[NC][68];
    __shared__ __align__(16) float wch[32][NC];
    __shared__ int invl[64];
    int b = blockIdx.y; int n0 = blockIdx.x * 64; int tid = threadIdx.x;
    if (tid < 64) invl[tid] = inv[b*NN + n0 + tid];
    __syncthreads();
    for (int i = tid; i < 64*NC; i += 256) {
        int n = i / NC, c = i % NC;
        attT[c][n] = attn[((size_t)b*NN + invl[n])*NC + c];
    }
    int nx = tid & 15, cy = tid >> 4;  // n = nx*4, c = cy*6
    float acc[4][6];
#pragma unroll
    for (int i = 0; i < 4; ++i)
#pragma unroll
        for (int j = 0; j < 6; ++j) acc[i][j] = 0.f;
    for (int kc = 0; kc < NC; kc += 32) {
        __syncthreads();
        for (int i = tid; i < 32*NC; i += 256) {
            int kk = i / NC, c = i % NC;
            wch[kk][c] = wpc[(kc+kk)*NC + c];
        }
        __syncthreads();
        for (int kk = 0; kk < 32; ++kk) {
            f4 a0 = *(const f4*)&attT[kc+kk][nx*4];
            float a[4] = {a0.x,a0.y,a0.z,a0.w};
            float2 w0 = *(const float2*)&wch[kk][cy*6];
            float2 w1 = *(const float2*)&wch[kk][cy*6+2];
            float2 w2 = *(const float2*)&wch[kk][cy*6+4];
            float bb[6] = {w0.x,w0.y,w1.x,w1.y,w2.x,w2.y};
#pragma unroll
            for (int i = 0; i < 4; ++i)
#pragma unroll
                for (int j = 0; j < 6; ++j) acc[i][j] += a[i]*bb[j];
        }
    }
#pragma unroll
    for (int j = 0; j < 6; ++j) {
        int c = cy*6 + j;
        size_t off = ((size_t)b*NC + c)*NN + n0 + nx*4;
        f4 xv = *(const f4*)&x[off];
        f4 o = {acc[0][j]+xv.x, acc[1][j]+xv.y, acc[2][j]+xv.z, acc[3][j]+xv.w};
        *(f4*)&xrt[off] = o;
    }
}

// ---------------------------------------------------------------------------
// LN2 + @W1 + b1 + GELU; reads xrt (b,c,n), writes z1t (b, m, n)
// ---------------------------------------------------------------------------
__global__ void __launch_bounds__(256) k_mlp1(
    const float* __restrict__ xrt, const float* __restrict__ g2, const float* __restrict__ b2v,
    const float* __restrict__ W1, const float* __restrict__ b1m,
    float* __restrict__ z1t) {
    __shared__ __align__(16) float xt[NC][68];
    __shared__ __align__(16) float wch[32][NMLP];
    __shared__ float meanl[64], rstdl[64];
    __shared__ float gl[NC], bl[NC];
    int b = blockIdx.y; int n0 = blockIdx.x*64; int tid = threadIdx.x;
    if (tid < NC) { gl[tid] = g2[tid]; bl[tid] = b2v[tid]; }
    for (int i = tid; i < NC*64; i += 256) {
        int c = i >> 6, n = i & 63;
        xt[c][n] = xrt[((size_t)b*NC + c)*NN + n0 + n];
    }
    __syncthreads();
    int lane = tid & 63, w = tid >> 6;
    for (int tk = 0; tk < 16; ++tk) {
        int tok = w*16 + tk;
        float a  = xt[lane][tok];
        float bb = (lane < 32) ? xt[64+lane][tok] : 0.f;
        float s = a + bb, sq = a*a + bb*bb;
#pragma unroll
        for (int off = 32; off > 0; off >>= 1) {
            s  += __shfl_xor(s, off);
            sq += __shfl_xor(sq, off);
        }
        if (lane == 0) {
            float mean = s * (1.0f/NC);
            float var  = sq * (1.0f/NC) - mean*mean;
            meanl[tok] = mean; rstdl[tok] = rsqrtf(var + 1e-5f);
        }
    }
    __syncthreads();
    for (int i = tid; i < NC*64; i += 256) {
        int c = i >> 6, n = i & 63;
        xt[c][n] = (xt[c][n]-meanl[n])*rstdl[n]*gl[c]+bl[c];
    }
    int nx = tid & 15, my = tid >> 4;  // n = nx*4, m = my*12
    float acc[4][12];
#pragma unroll
    for (int i = 0; i < 4; ++i)
#pragma unroll
        for (int j = 0; j < 12; ++j) acc[i][j] = 0.f;
    for (int kc = 0; kc < NC; kc += 32) {
        __syncthreads();
        for (int i = tid; i < 32*NMLP; i += 256) {
            int kk = i / NMLP, c = i % NMLP;
            wch[kk][c] = W1[(kc+kk)*NMLP + c];
        }
        __syncthreads();
        for (int kk = 0; kk < 32; ++kk) {
            f4 a0 = *(const f4*)&xt[kc+kk][nx*4];
            float a[4] = {a0.x,a0.y,a0.z,a0.w};
            f4 w0 = *(const f4*)&wch[kk][my*12];
            f4 w1 = *(const f4*)&wch[kk][my*12+4];
            f4 w2 = *(const f4*)&wch[kk][my*12+8];
            float bb[12] = {w0.x,w0.y,w0.z,w0.w,w1.x,w1.y,w1.z,w1.w,w2.x,w2.y,w2.z,w2.w};
#pragma unroll
            for (int i = 0; i < 4; ++i)
#pragma unroll
                for (int j = 0; j < 12; ++j) acc[i][j] += a[i]*bb[j];
        }
    }
#pragma unroll
    for (int j = 0; j < 12; ++j) {
        int mm = my*12 + j;
        float bias = b1m[mm];
        size_t off = ((size_t)b*NMLP + mm)*NN + n0 + nx*4;
        f4 o = { gelu_f(acc[0][j]+bias), gelu_f(acc[1][j]+bias),
                 gelu_f(acc[2][j]+bias), gelu_f(acc[3][j]+bias) };
        *(f4*)&z1t[off] = o;
    }
}

// ---------------------------------------------------------------------------
// Depthwise 5x5x5 conv (pad 2) + GELU + add z1; z2t (b,m,n), register-blocked
// ---------------------------------------------------------------------------
__global__ void __launch_bounds__(256) k_dwconv(
    const float* __restrict__ z1t, const float* __restrict__ Wdw, const float* __restrict__ bdw,
    float* __restrict__ z2t) {
    __shared__ __align__(16) float tin[ND][20][72];
    __shared__ float wl[128];
    int ht = blockIdx.x, mch = blockIdx.y, b = blockIdx.z;
    int h0 = ht*16; int tid = threadIdx.x;
    if (tid < 125) wl[tid] = Wdw[mch*125 + tid];
    const float* src = &z1t[((size_t)b*NMLP + mch)*NN];
    for (int i = tid; i < ND*20*68; i += 256) {
        int dd = i / (20*68); int r = i % (20*68); int hh = r / 68; int ww = r % 68;
        int gh = h0 + hh - 2, gw = ww - 2;
        float v = 0.f;
        if ((unsigned)gh < 64u && (unsigned)gw < 64u) v = src[dd*4096 + gh*64 + gw];
        tin[dd][hh][ww] = v;
    }
    __syncthreads();
    int rowid = tid >> 1; int od = rowid >> 4; int ohl = rowid & 15; int wb = (tid & 1)*32;
    float acc[32];
#pragma unroll
    for (int o = 0; o < 32; ++o) acc[o] = 0.f;
    for (int kd = 0; kd < 5; ++kd) {
        int id = od + kd - 2;
        if ((unsigned)id >= (unsigned)ND) continue;
#pragma unroll
        for (int kh = 0; kh < 5; ++kh) {
            const float* rp = &tin[id][ohl+kh][wb];
            float seg[36];
#pragma unroll
            for (int i = 0; i < 9; ++i) *(f4*)&seg[i*4] = *(const f4*)&rp[i*4];
#pragma unroll
            for (int kw = 0; kw < 5; ++kw) {
                float wt = wl[kd*25 + kh*5 + kw];
#pragma unroll
                for (int o = 0; o < 32; ++o) acc[o] += seg[o+kw]*wt;
            }
        }
    }
    float bias = bdw[mch];
    float* dst = &z2t[((size_t)b*NMLP + mch)*NN + od*4096 + (size_t)(h0+ohl)*64 + wb];
    const float* ctr = &tin[od][ohl+2][wb+2];
#pragma unroll
    for (int o4 = 0; o4 < 32; o4 += 4) {
        f4 ov = { ctr[o4+0] + gelu_f(acc[o4+0]+bias),
                  ctr[o4+1] + gelu_f(acc[o4+1]+bias),
                  ctr[o4+2] + gelu_f(acc[o4+2]+bias),
                  ctr[o4+3] + gelu_f(acc[o4+3]+bias) };
        *(f4*)&dst[o4] = ov;
    }
}

// ---------------------------------------------------------------------------
// Final: out(b,c,n) = z2 @ W2 + b2 + xrt ; 128-token tile, thread = 8n x 6c
// ---------------------------------------------------------------------------
__global__ void __launch_bounds__(256) k_final(
    const float* __restrict__ z2t, const float* __restrict__ W2, const float* __restrict__ b2m,
    const float* __restrict__ xrt, float* __restrict__ out) {
    __shared__ __align__(16) float zch[32][132];
    __shared__ __align__(16) float wch[32][NC];
    int b = blockIdx.y; int n0 = blockIdx.x*128; int tid = threadIdx.x;
    int nx = tid & 15, cy = tid >> 4;   // n = nx*8, c = cy*6
    float acc[8][6];
#pragma unroll
    for (int i = 0; i < 8; ++i)
#pragma unroll
        for (int j = 0; j < 6; ++j) acc[i][j] = 0.f;
    for (int kc = 0; kc < NMLP; kc += 32) {
        __syncthreads();
        for (int i = tid; i < 32*128; i += 256) {
            int kk = i >> 7, n = i & 127;
            zch[kk][n] = z2t[((size_t)b*NMLP + kc + kk)*NN + n0 + n];
        }
        for (int i = tid; i < 32*NC; i += 256) {
            int kk = i / NC, c = i % NC;
            wch[kk][c] = W2[(kc+kk)*NC + c];
        }
        __syncthreads();
        for (int kk = 0; kk < 32; ++kk) {
            f4 a0 = *(const f4*)&zch[kk][nx*8];
            f4 a1 = *(const f4*)&zch[kk][nx*8+4];
            float a[8] = {a0.x,a0.y,a0.z,a0.w,a1.x,a1.y,a1.z,a1.w};
            float2 w0 = *(const float2*)&wch[kk][cy*6];
            float2 w1 = *(const float2*)&wch[kk][cy*6+2];
            float2 w2 = *(const float2*)&wch[kk][cy*6+4];
            float bb[6] = {w0.x,w0.y,w1.x,w1.y,w2.x,w2.y};
#pragma unroll
            for (int i = 0; i < 8; ++i)
#pragma unroll
                for (int j = 0; j < 6; ++j) acc[i][j] += a[i]*bb[j];
        }
    }
#pragma unroll
    for (int j = 0; j < 6; ++j) {
        int c = cy*6 + j;
        float bias = b2m[c];
        size_t off = ((size_t)b*NC + c)*NN + n0 + nx*8;
        f4 x0 = *(const f4*)&xrt[off];
        f4 x1 = *(const f4*)&xrt[off+4];
        f4 o0 = {acc[0][j]+bias+x0.x, acc[1][j]+bias+x0.y, acc[2][j]+bias+x0.z, acc[3][j]+bias+x0.w};
        f4 o1 = {acc[4][j]+bias+x1.x, acc[5][j]+bias+x1.y, acc[6][j]+bias+x1.z, acc[7][j]+bias+x1.w};
        *(f4*)&out[off]   = o0;
        *(f4*)&out[off+4] = o1;
    }
}

// ---------------------------------------------------------------------------
extern "C" void kernel_launch(void* const* d_in, const int* in_sizes, int n_in,
                              void* d_out, int out_size, void* d_ws, size_t ws_size,
                              hipStream_t stream) {
    (void)in_sizes; (void)n_in; (void)out_size; (void)ws_size;
    const float* x     = (const float*)d_in[0];
    const float* means = (const float*)d_in[1];
    const float* ln1_g = (const float*)d_in[2];
    const float* ln1_b = (const float*)d_in[3];
    const float* Wkg   = (const float*)d_in[4];
    const float* Wvg   = (const float*)d_in[5];
    const float* Wq    = (const float*)d_in[6];
    const float* Wk    = (const float*)d_in[7];
    const float* Wv    = (const float*)d_in[8];
    const float* Wproj = (const float*)d_in[9];
    const float* Wconv = (const float*)d_in[10];
    const float* ln2_g = (const float*)d_in[11];
    const float* ln2_b = (const float*)d_in[12];
    const float* W1    = (const float*)d_in[13];
    const float* b1    = (const float*)d_in[14];
    const float* Wdw   = (const float*)d_in[15];
    const float* bdw   = (const float*)d_in[16];
    const float* W2    = (const float*)d_in[17];
    const float* b2    = (const float*)d_in[18];
    float* out = (float*)d_out;

    float* ws = (float*)d_ws;
    const size_t SZ = (size_t)NB*NN*NC;
    float* xn   = ws;
    float* qs   = ws + SZ;
    float* ks   = ws + 2*SZ;
    float* vs   = ws + 3*SZ;
    float* attn = ws + 4*SZ;
    float* xrt  = ws;          // reuse xn (dead after k_qkv)
    float* z1t  = ws + SZ;     // reuse qs,ks (dead after k_attn)
    float* z2t  = ws + 3*SZ;   // reuse vs,attn
    float* faux = ws + 5*SZ;
    float* mnn  = faux;            // 768
    float* gdot = faux + 768;      // 8
    float* bdot = faux + 776;      // 8
    float* kg   = faux + 784;      // 768
    float* vg   = faux + 1552;     // 768
    float* wpc  = faux + 2320;     // 9216 -> ends at 11536
    int* iaux   = (int*)(faux + 11536);
    int* belong = iaux;                  // NB*NN
    int* idx    = iaux + NB*NN;          // NB*NN
    int* inv    = iaux + 2*NB*NN;        // NB*NN
    int* hist   = iaux + 3*NB*NN;        // NB*128*8
    int* baseb  = hist + NB*128*NTOK;    // NB*128*8

    k_precompute<<<dim3(5), dim3(256), 0, stream>>>(
        means, ln1_g, ln1_b, Wkg, Wvg, Wproj, Wconv, mnn, gdot, bdot, kg, vg, wpc);
    k_ln1<<<dim3(NN/64, NB), dim3(256), 0, stream>>>(
        x, ln1_g, ln1_b, mnn, gdot, bdot, xn, belong);
    k_hist<<<dim3(NN/256, NB), dim3(256), 0, stream>>>(belong, hist);
    k_scan<<<dim3(NB), dim3(256), 0, stream>>>(hist, baseb);
    k_scatteridx<<<dim3(NN/256, NB), dim3(256), 0, stream>>>(belong, baseb, idx, inv);
    k_qkv<<<dim3(NN/128, NB), dim3(256), 0, stream>>>(xn, idx, Wq, Wk, Wv, qs, ks, vs);
    k_attn<<<dim3(NGRP, NHEADS, NB), dim3(256), 0, stream>>>(qs, ks, vs, kg, vg, attn);
    k_scatproj<<<dim3(NN/64, NB), dim3(256), 0, stream>>>(attn, inv, wpc, x, xrt);
    k_mlp1<<<dim3(NN/64, NB), dim3(256), 0, stream>>>(xrt, ln2_g, ln2_b, W1, b1, z1t);
    k_dwconv<<<dim3(4, NMLP, NB), dim3(256), 0, stream>>>(z1t, Wdw, bdw, z2t);
    k_final<<<dim3(NN/128, NB), dim3(256), 0, stream>>>(z2t, W2, b2, xrt, out);
}

// Round 10
// 641.611 us; speedup vs baseline: 1.0066x; 1.0066x over previous
//
#include <hip/hip_runtime.h>
#include <math.h>

#define NB 2
#define NC 96
#define ND 8
#define NHH 64
#define NWW 64
#define NN 32768          // ND*NHH*NWW
#define NTOK 8
#define NHEADS 6
#define GSZ 128
#define NGRP 256          // NN/GSZ
#define NMLP 192

typedef float4 f4;

__device__ __forceinline__ float gelu_f(float x) {
    return 0.5f * x * (1.0f + erff(x * 0.70710678118654752440f));
}

// ---------------------------------------------------------------------------
// Precompute (grid=5): blk0: normalized means, gdot/bdot, kg/vg.
// blk1..4: wpc = Wproj @ Wconv, 24 rows each, fully LDS-staged.
// ---------------------------------------------------------------------------
__global__ void __launch_bounds__(256) k_precompute(
    const float* __restrict__ means, const float* __restrict__ g1, const float* __restrict__ b1v,
    const float* __restrict__ Wkg, const float* __restrict__ Wvg,
    const float* __restrict__ Wproj, const float* __restrict__ Wconv,
    float* __restrict__ mnn, float* __restrict__ gdot, float* __restrict__ bdot,
    float* __restrict__ kg, float* __restrict__ vg, float* __restrict__ wpc) {
    int blk = blockIdx.x; int tid = threadIdx.x;
    if (blk == 0) {
        __shared__ float mlds[NTOK*NC];
        __shared__ float glds[NC], blds[NC];
        for (int i = tid; i < NTOK*NC; i += 256) mlds[i] = means[i];
        if (tid < NC) { glds[tid] = g1[tid]; blds[tid] = b1v[tid]; }
        __syncthreads();
        if (tid < NTOK) {
            float ss = 0.f;
            for (int c = 0; c < NC; ++c) { float v = mlds[tid*NC+c]; ss += v*v; }
            float inv = 1.0f / fmaxf(sqrtf(ss), 1e-12f);
            float gd = 0.f, bd = 0.f;
            for (int c = 0; c < NC; ++c) {
                float v = mlds[tid*NC+c] * inv;
                mnn[tid*NC+c] = v;
                gd += glds[c]*v; bd += blds[c]*v;
            }
            gdot[tid] = gd; bdot[tid] = bd;
        }
        // kg/vg: layout [h][t][e], e<16
        for (int i = tid; i < NHEADS*NTOK*16; i += 256) {
            int h = i / (NTOK*16); int r = i % (NTOK*16); int t = r / 16; int e = r % 16;
            float sk = 0.f, sv = 0.f;
            for (int c = 0; c < NC; ++c) {
                float mv = mlds[t*NC+c];
                sk += mv * Wkg[c*NC + h*16+e];
                sv += mv * Wvg[c*NC + h*16+e];
            }
            kg[i] = sk; vg[i] = sv;
        }
    } else {
        int r0 = (blk-1)*24;
        __shared__ float wcv[NC][NC];
        __shared__ float wpl[24][NC];
        for (int i = tid; i < NC*NC; i += 256) wcv[i/NC][i%NC] = Wconv[i];
        for (int i = tid; i < 24*NC; i += 256) wpl[i/NC][i%NC] = Wproj[(r0 + i/NC)*NC + i%NC];
        __syncthreads();
        for (int o = tid; o < 24*NC; o += 256) {
            int r = o / NC, c = o % NC;
            float s = 0.f;
            for (int k = 0; k < NC; ++k) s += wpl[r][k]*wcv[k][c];
            wpc[(r0+r)*NC + c] = s;
        }
    }
}

// ---------------------------------------------------------------------------
// LN1 (reads x in (b,c,n), writes xn in (b,n,c)) fused with cluster argmax.
// ---------------------------------------------------------------------------
__global__ void __launch_bounds__(256) k_ln1(
    const float* __restrict__ x, const float* __restrict__ g1, const float* __restrict__ b1v,
    const float* __restrict__ mnn, const float* __restrict__ gdot, const float* __restrict__ bdot,
    float* __restrict__ xn, int* __restrict__ belong) {
    __shared__ __align__(16) float xt[NC][68];
    __shared__ float meanl[64], rstdl[64];
    __shared__ float gl[NC], bl[NC], gdl[NTOK], bdl[NTOK];
    int b = blockIdx.y; int n0 = blockIdx.x * 64;
    int tid = threadIdx.x;
    if (tid < NC) { gl[tid] = g1[tid]; bl[tid] = b1v[tid]; }
    if (tid >= NC && tid < NC+NTOK) { gdl[tid-NC] = gdot[tid-NC]; bdl[tid-NC] = bdot[tid-NC]; }
    for (int i = tid; i < NC*64; i += 256) {
        int c = i >> 6, n = i & 63;
        xt[c][n] = x[((size_t)b*NC + c)*NN + n0 + n];
    }
    __syncthreads();
    int lane = tid & 63, w = tid >> 6;
    float ga = gl[lane];
    float gb = (lane < 32) ? gl[64+lane] : 0.f;
    float ma[NTOK], mb[NTOK];
#pragma unroll
    for (int t = 0; t < NTOK; ++t) {
        ma[t] = mnn[t*NC + lane];
        mb[t] = (lane < 32) ? mnn[t*NC + 64 + lane] : 0.f;
    }
    for (int tk = 0; tk < 16; ++tk) {
        int tok = w*16 + tk;
        float a  = xt[lane][tok];
        float bb = (lane < 32) ? xt[64+lane][tok] : 0.f;
        float red[10];
        red[0] = a + bb;
        red[1] = a*a + bb*bb;
        float ag = a*ga, bg = bb*gb;
#pragma unroll
        for (int t = 0; t < NTOK; ++t) red[2+t] = ag*ma[t] + bg*mb[t];
#pragma unroll
        for (int off = 32; off > 0; off >>= 1) {
#pragma unroll
            for (int r = 0; r < 10; ++r) red[r] += __shfl_xor(red[r], off);
        }
        if (lane == 0) {
            float mean = red[0] * (1.0f/NC);
            float var  = red[1] * (1.0f/NC) - mean*mean;
            float rstd = rsqrtf(var + 1e-5f);
            meanl[tok] = mean; rstdl[tok] = rstd;
            int best = 0; float bestv = -1e30f;
#pragma unroll
            for (int t = 0; t < NTOK; ++t) {
                float sc = rstd*(red[2+t] - mean*gdl[t]) + bdl[t];
                if (sc > bestv) { bestv = sc; best = t; }
            }
            belong[b*NN + n0 + tok] = best;
        }
    }
    __syncthreads();
    for (int i = tid; i < 64*NC; i += 256) {
        int n = i / NC, c = i % NC;
        float v = (xt[c][n] - meanl[n]) * rstdl[n] * gl[c] + bl[c];
        xn[((size_t)b*NN + n0 + n)*NC + c] = v;
    }
}

// ---------------------------------------------------------------------------
// Stable counting sort of `belong` (values 0..7): hist -> scan -> scatter
// ---------------------------------------------------------------------------
__global__ void __launch_bounds__(256) k_hist(const int* __restrict__ belong, int* __restrict__ hist) {
    int b = blockIdx.y, ch = blockIdx.x, tid = threadIdx.x;
    __shared__ int wc[4][NTOK];
    int myt = belong[b*NN + ch*256 + tid];
    int w = tid >> 6, lane = tid & 63;
#pragma unroll
    for (int t = 0; t < NTOK; ++t) {
        unsigned long long m = __ballot(myt == t);
        if (lane == 0) wc[w][t] = __popcll(m);
    }
    __syncthreads();
    if (tid < NTOK) hist[(b*128 + ch)*NTOK + tid] = wc[0][tid]+wc[1][tid]+wc[2][tid]+wc[3][tid];
}

__global__ void __launch_bounds__(256) k_scan(const int* __restrict__ hist, int* __restrict__ base) {
    int b = blockIdx.x, tid = threadIdx.x;
    __shared__ int A[NTOK][128], Bf[NTOK][128], orig[NTOK][128];
    __shared__ int cb[NTOK];
    for (int i = tid; i < NTOK*128; i += 256) {
        int t = i >> 7, ch = i & 127;
        int v = hist[(b*128 + ch)*NTOK + t];
        A[t][ch] = v; orig[t][ch] = v;
    }
    __syncthreads();
    for (int d = 1; d < 128; d <<= 1) {
        for (int i = tid; i < NTOK*128; i += 256) {
            int t = i >> 7, ch = i & 127;
            Bf[t][ch] = A[t][ch] + ((ch >= d) ? A[t][ch-d] : 0);
        }
        __syncthreads();
        for (int i = tid; i < NTOK*128; i += 256) {
            int t = i >> 7, ch = i & 127;
            A[t][ch] = Bf[t][ch];
        }
        __syncthreads();
    }
    if (tid == 0) {
        int run = 0;
        for (int t = 0; t < NTOK; ++t) { cb[t] = run; run += A[t][127]; }
    }
    __syncthreads();
    for (int i = tid; i < NTOK*128; i += 256) {
        int t = i >> 7, ch = i & 127;
        base[(b*128 + ch)*NTOK + t] = cb[t] + A[t][ch] - orig[t][ch];
    }
}

__global__ void __launch_bounds__(256) k_scatteridx(
    const int* __restrict__ belong, const int* __restrict__ base,
    int* __restrict__ idx, int* __restrict__ inv) {
    int b = blockIdx.y, ch = blockIdx.x, tid = threadIdx.x;
    __shared__ int wc[4][NTOK];
    __shared__ int woff[4][NTOK];
    int n = ch*256 + tid;
    int myt = belong[b*NN + n];
    int w = tid >> 6, lane = tid & 63;
    unsigned long long mymask = 0;
#pragma unroll
    for (int t = 0; t < NTOK; ++t) {
        unsigned long long m = __ballot(myt == t);
        if (myt == t) mymask = m;
        if (lane == 0) wc[w][t] = __popcll(m);
    }
    __syncthreads();
    if (tid < 32) {
        int w2 = tid >> 3, t = tid & 7;
        int s = 0;
        for (int ww = 0; ww < w2; ++ww) s += wc[ww][t];
        woff[w2][t] = s;
    }
    __syncthreads();
    int rank = __popcll(mymask & ((1ull << lane) - 1ull));
    int p = base[(b*128+ch)*NTOK + myt] + woff[w][myt] + rank;
    idx[b*NN + p] = n;
    inv[b*NN + n] = p;
}

// ---------------------------------------------------------------------------
// q/k/v = gather(xn, idx) @ {Wq,Wk,Wv}; 128-row tile, thread = 8n x 6c
// ---------------------------------------------------------------------------
__global__ void __launch_bounds__(256) k_qkv(
    const float* __restrict__ xn, const int* __restrict__ idx,
    const float* __restrict__ Wq, const float* __restrict__ Wk, const float* __restrict__ Wv,
    float* __restrict__ qs, float* __restrict__ ks, float* __restrict__ vs) {
    __shared__ __align__(16) float xnT[NC][132];
    __shared__ __align__(16) float wch[32][NC];
    __shared__ int idxl[128];
    int b = blockIdx.y; int p0 = blockIdx.x * 128; int tid = threadIdx.x;
    if (tid < 128) idxl[tid] = idx[b*NN + p0 + tid];
    __syncthreads();
    for (int i = tid; i < 128*NC; i += 256) {
        int p = i / NC, c = i % NC;
        xnT[c][p] = xn[((size_t)b*NN + idxl[p])*NC + c];
    }
    int cx = tid & 15, ny = tid >> 4;   // c = cx*6, n = ny*8
    const float* Ws[3] = {Wq, Wk, Wv};
    float* Os[3] = {qs, ks, vs};
    for (int m = 0; m < 3; ++m) {
        float acc[8][6];
#pragma unroll
        for (int i = 0; i < 8; ++i)
#pragma unroll
            for (int j = 0; j < 6; ++j) acc[i][j] = 0.f;
        const float* W = Ws[m];
        for (int kc = 0; kc < NC; kc += 32) {
            __syncthreads();
            for (int i = tid; i < 32*NC; i += 256) {
                int kk = i / NC, c = i % NC;
                wch[kk][c] = W[(kc+kk)*NC + c];
            }
            __syncthreads();
            for (int kk = 0; kk < 32; ++kk) {
                f4 a0 = *(const f4*)&xnT[kc+kk][ny*8];
                f4 a1 = *(const f4*)&xnT[kc+kk][ny*8+4];
                float a[8] = {a0.x,a0.y,a0.z,a0.w,a1.x,a1.y,a1.z,a1.w};
                float2 w0 = *(const float2*)&wch[kk][cx*6];
                float2 w1 = *(const float2*)&wch[kk][cx*6+2];
                float2 w2 = *(const float2*)&wch[kk][cx*6+4];
                float bb[6] = {w0.x,w0.y,w1.x,w1.y,w2.x,w2.y};
#pragma unroll
                for (int i = 0; i < 8; ++i)
#pragma unroll
                    for (int j = 0; j < 6; ++j) acc[i][j] += a[i]*bb[j];
            }
        }
        float* O = Os[m];
#pragma unroll
        for (int i = 0; i < 8; ++i) {
            size_t off = ((size_t)b*NN + p0 + ny*8 + i)*NC + cx*6;
            float2 s0 = {acc[i][0], acc[i][1]};
            float2 s1 = {acc[i][2], acc[i][3]};
            float2 s2 = {acc[i][4], acc[i][5]};
            *(float2*)&O[off]   = s0;
            *(float2*)&O[off+2] = s1;
            *(float2*)&O[off+4] = s2;
        }
    }
}

// ---------------------------------------------------------------------------
// Windowed attention v4: thread = (row-pair, key-quarter), with STRIDED key
// assignment: quarter qt handles keys == qt (mod 4). Round-9's contiguous
// quarters (k0=qt*64) made all 4 lane-groups hit identical banks (64-row
// offset == 0 mod 32 words -> 2.5e7 bank conflicts, 164->179us regression).
// Stride-4 rows differ by 1 -> even/odd rows split banks {0..15}/{16..31}
// within each 32-lane half-cycle -> zero conflicts. Softmax over a key
// subset is permutation-invariant, so the shfl merge tree is unchanged.
// ---------------------------------------------------------------------------
__global__ void __launch_bounds__(256) k_attn(
    const float* __restrict__ qs, const float* __restrict__ ks, const float* __restrict__ vs,
    const float* __restrict__ kg, const float* __restrict__ vg,
    float* __restrict__ attn) {
    __shared__ __align__(16) f4 kt[256][4];
    __shared__ __align__(16) f4 vt[256][4];
    __shared__ __align__(16) f4 kgs[NTOK][4];
    __shared__ __align__(16) f4 vgs[NTOK][4];
    int g = blockIdx.x, h = blockIdx.y, b = blockIdx.z;
    int tid = threadIdx.x;
    for (int i = tid; i < 1024; i += 256) {
        int r = i >> 2, c = i & 3;
        int src = g*GSZ + r;
        if (g == NGRP-1 && r >= GSZ) src = NN - 1 - (r - GSZ);
        size_t off = ((size_t)b*NN + src)*NC + h*16 + c*4;
        kt[r][c] = *(const f4*)&ks[off];
        vt[r][c] = *(const f4*)&vs[off];
    }
    if (tid < 32) {
        int t = tid >> 2, c = tid & 3;
        kgs[t][c] = *(const f4*)&kg[(h*NTOK + t)*16 + c*4];
        vgs[t][c] = *(const f4*)&vg[(h*NTOK + t)*16 + c*4];
    }
    int wv = tid >> 6, lane = tid & 63;
    int pr = lane & 15;       // row-pair index within wave
    int qt = lane >> 4;       // key residue class 0..3 (keys == qt mod 4)
    int r0 = wv*32 + pr*2;    // rows r0, r0+1
    float qv0[16], qv1[16];
    {
        const f4* qp0 = (const f4*)&qs[((size_t)b*NN + g*GSZ + r0)*NC + h*16];
        const f4* qp1 = (const f4*)&qs[((size_t)b*NN + g*GSZ + r0 + 1)*NC + h*16];
#pragma unroll
        for (int i = 0; i < 4; ++i) {
            f4 t0 = qp0[i], t1 = qp1[i];
            qv0[i*4+0]=t0.x*0.25f; qv0[i*4+1]=t0.y*0.25f; qv0[i*4+2]=t0.z*0.25f; qv0[i*4+3]=t0.w*0.25f;
            qv1[i*4+0]=t1.x*0.25f; qv1[i*4+1]=t1.y*0.25f; qv1[i*4+2]=t1.z*0.25f; qv1[i*4+3]=t1.w*0.25f;
        }
    }
    __syncthreads();
    float m0 = -1e30f, l0 = 0.f, m1 = -1e30f, l1 = 0.f;
    float acc0[16], acc1[16];
#pragma unroll
    for (int e = 0; e < 16; ++e) { acc0[e] = 0.f; acc1[e] = 0.f; }
    for (int c8 = 0; c8 < 8; ++c8) {
        float s0[8], s1[8];
#pragma unroll
        for (int j = 0; j < 8; ++j) {
            const f4* kp = &kt[(c8*8 + j)*4 + qt][0];
            f4 ka = kp[0], kb = kp[1], kc = kp[2], kd = kp[3];
            s0[j] = qv0[0]*ka.x + qv0[1]*ka.y + qv0[2]*ka.z + qv0[3]*ka.w
                  + qv0[4]*kb.x + qv0[5]*kb.y + qv0[6]*kb.z + qv0[7]*kb.w
                  + qv0[8]*kc.x + qv0[9]*kc.y + qv0[10]*kc.z + qv0[11]*kc.w
                  + qv0[12]*kd.x + qv0[13]*kd.y + qv0[14]*kd.z + qv0[15]*kd.w;
            s1[j] = qv1[0]*ka.x + qv1[1]*ka.y + qv1[2]*ka.z + qv1[3]*ka.w
                  + qv1[4]*kb.x + qv1[5]*kb.y + qv1[6]*kb.z + qv1[7]*kb.w
                  + qv1[8]*kc.x + qv1[9]*kc.y + qv1[10]*kc.z + qv1[11]*kc.w
                  + qv1[12]*kd.x + qv1[13]*kd.y + qv1[14]*kd.z + qv1[15]*kd.w;
        }
        float cm0 = fmaxf(fmaxf(fmaxf(s0[0],s0[1]), fmaxf(s0[2],s0[3])),
                          fmaxf(fmaxf(s0[4],s0[5]), fmaxf(s0[6],s0[7])));
        float cm1 = fmaxf(fmaxf(fmaxf(s1[0],s1[1]), fmaxf(s1[2],s1[3])),
                          fmaxf(fmaxf(s1[4],s1[5]), fmaxf(s1[6],s1[7])));
        float nm0 = fmaxf(m0, cm0), nm1 = fmaxf(m1, cm1);
        float corr0 = __expf(m0 - nm0), corr1 = __expf(m1 - nm1);
        m0 = nm0; m1 = nm1;
        l0 *= corr0; l1 *= corr1;
#pragma unroll
        for (int e = 0; e < 16; ++e) { acc0[e] *= corr0; acc1[e] *= corr1; }
#pragma unroll
        for (int j = 0; j < 8; ++j) {
            float p0 = __expf(s0[j] - m0);
            float p1 = __expf(s1[j] - m1);
            l0 += p0; l1 += p1;
            const f4* vp = &vt[(c8*8 + j)*4 + qt][0];
            f4 va = vp[0], vb = vp[1], vc = vp[2], vd = vp[3];
            acc0[0] += p0*va.x; acc0[1] += p0*va.y; acc0[2] += p0*va.z; acc0[3] += p0*va.w;
            acc0[4] += p0*vb.x; acc0[5] += p0*vb.y; acc0[6] += p0*vb.z; acc0[7] += p0*vb.w;
            acc0[8] += p0*vc.x; acc0[9] += p0*vc.y; acc0[10] += p0*vc.z; acc0[11] += p0*vc.w;
            acc0[12] += p0*vd.x; acc0[13] += p0*vd.y; acc0[14] += p0*vd.z; acc0[15] += p0*vd.w;
            acc1[0] += p1*va.x; acc1[1] += p1*va.y; acc1[2] += p1*va.z; acc1[3] += p1*va.w;
            acc1[4] += p1*vb.x; acc1[5] += p1*vb.y; acc1[6] += p1*vb.z; acc1[7] += p1*vb.w;
            acc1[8] += p1*vc.x; acc1[9] += p1*vc.y; acc1[10] += p1*vc.z; acc1[11] += p1*vc.w;
            acc1[12] += p1*vd.x; acc1[13] += p1*vd.y; acc1[14] += p1*vd.z; acc1[15] += p1*vd.w;
        }
    }
    // merge 4 quarter-states per row via shfl_xor tree (offsets 16, 32)
#pragma unroll
    for (int off = 16; off <= 32; off <<= 1) {
        float om = __shfl_xor(m0, off), ol = __shfl_xor(l0, off);
        float mw = fmaxf(m0, om);
        float e0 = __expf(m0 - mw), e1 = __expf(om - mw);
        l0 = l0*e0 + ol*e1; m0 = mw;
#pragma unroll
        for (int e = 0; e < 16; ++e) {
            float oa = __shfl_xor(acc0[e], off);
            acc0[e] = acc0[e]*e0 + oa*e1;
        }
        om = __shfl_xor(m1, off); ol = __shfl_xor(l1, off);
        mw = fmaxf(m1, om);
        e0 = __expf(m1 - mw); e1 = __expf(om - mw);
        l1 = l1*e0 + ol*e1; m1 = mw;
#pragma unroll
        for (int e = 0; e < 16; ++e) {
            float oa = __shfl_xor(acc1[e], off);
            acc1[e] = acc1[e]*e0 + oa*e1;
        }
    }
    // select this lane's tail row (qt==0 -> r0, qt==1 -> r0+1) via cndmask
    float qvs[16], accs[16];
#pragma unroll
    for (int e = 0; e < 16; ++e) {
        qvs[e]  = (qt == 1) ? qv1[e]  : qv0[e];
        accs[e] = (qt == 1) ? acc1[e] : acc0[e];
    }
    float ls = (qt == 1) ? l1 : l0;
    if (qt < 2) {
        // global attention over 8 cluster tokens for row r0+qt
        float m2 = -1e30f, l2 = 0.f;
        float a2[16];
#pragma unroll
        for (int e = 0; e < 16; ++e) a2[e] = 0.f;
#pragma unroll
        for (int t = 0; t < NTOK; ++t) {
            f4 ka = kgs[t][0], kb = kgs[t][1], kc = kgs[t][2], kd = kgs[t][3];
            float s = qvs[0]*ka.x + qvs[1]*ka.y + qvs[2]*ka.z + qvs[3]*ka.w
                    + qvs[4]*kb.x + qvs[5]*kb.y + qvs[6]*kb.z + qvs[7]*kb.w
                    + qvs[8]*kc.x + qvs[9]*kc.y + qvs[10]*kc.z + qvs[11]*kc.w
                    + qvs[12]*kd.x + qvs[13]*kd.y + qvs[14]*kd.z + qvs[15]*kd.w;
            float nm2 = fmaxf(m2, s);
            float corr = __expf(m2 - nm2);
            m2 = nm2;
            l2 *= corr;
            float p = __expf(s - m2);
            l2 += p;
            f4 va = vgs[t][0], vb = vgs[t][1], vc = vgs[t][2], vd = vgs[t][3];
#pragma unroll
            for (int e = 0; e < 16; ++e) a2[e] *= corr;
            a2[0] += p*va.x; a2[1] += p*va.y; a2[2] += p*va.z; a2[3] += p*va.w;
            a2[4] += p*vb.x; a2[5] += p*vb.y; a2[6] += p*vb.z; a2[7] += p*vb.w;
            a2[8] += p*vc.x; a2[9] += p*vc.y; a2[10] += p*vc.z; a2[11] += p*vc.w;
            a2[12] += p*vd.x; a2[13] += p*vd.y; a2[14] += p*vd.z; a2[15] += p*vd.w;
        }
        float inv2 = 1.f / l2;
        float invw = 1.f / ls;
        float o[16];
#pragma unroll
        for (int e = 0; e < 16; ++e) o[e] = accs[e]*invw + a2[e]*inv2;
        f4* op = (f4*)&attn[((size_t)b*NN + g*GSZ + r0 + qt)*NC + h*16];
#pragma unroll
        for (int i = 0; i < 4; ++i) {
            f4 t = {o[i*4+0], o[i*4+1], o[i*4+2], o[i*4+3]};
            op[i] = t;
        }
    }
}

// ---------------------------------------------------------------------------
// Scatter back (inv), @ (Wproj@Wconv), + residual x; writes xrt in (b,c,n)
// ---------------------------------------------------------------------------
__global__ void __launch_bounds__(256) k_scatproj(
    const float* __restrict__ attn, const int* __restrict__ inv,
    const float* __restrict__ wpc, const float* __restrict__ x,
    float* __restrict__ xrt) {
    __shared__ __align__(16) float attT[NC][68];
    __shared__ __align__(16) float wch[32][NC];
    __shared__ int invl[64];
    int b = blockIdx.y; int n0 = blockIdx.x * 64; int tid = threadIdx.x;
    if (tid < 64) invl[tid] = inv[b*NN + n0 + tid];
    __syncthreads();
    for (int i = tid; i < 64*NC; i += 256) {
        int n = i / NC, c = i % NC;
        attT[c][n] = attn[((size_t)b*NN + invl[n])*NC + c];
    }
    int nx = tid & 15, cy = tid >> 4;  // n = nx*4, c = cy*6
    float acc[4][6];
#pragma unroll
    for (int i = 0; i < 4; ++i)
#pragma unroll
        for (int j = 0; j < 6; ++j) acc[i][j] = 0.f;
    for (int kc = 0; kc < NC; kc += 32) {
        __syncthreads();
        for (int i = tid; i < 32*NC; i += 256) {
            int kk = i / NC, c = i % NC;
            wch[kk][c] = wpc[(kc+kk)*NC + c];
        }
        __syncthreads();
        for (int kk = 0; kk < 32; ++kk) {
            f4 a0 = *(const f4*)&attT[kc+kk][nx*4];
            float a[4] = {a0.x,a0.y,a0.z,a0.w};
            float2 w0 = *(const float2*)&wch[kk][cy*6];
            float2 w1 = *(const float2*)&wch[kk][cy*6+2];
            float2 w2 = *(const float2*)&wch[kk][cy*6+4];
            float bb[6] = {w0.x,w0.y,w1.x,w1.y,w2.x,w2.y};
#pragma unroll
            for (int i = 0; i < 4; ++i)
#pragma unroll
                for (int j = 0; j < 6; ++j) acc[i][j] += a[i]*bb[j];
        }
    }
#pragma unroll
    for (int j = 0; j < 6; ++j) {
        int c = cy*6 + j;
        size_t off = ((size_t)b*NC + c)*NN + n0 + nx*4;
        f4 xv = *(const f4*)&x[off];
        f4 o = {acc[0][j]+xv.x, acc[1][j]+xv.y, acc[2][j]+xv.z, acc[3][j]+xv.w};
        *(f4*)&xrt[off] = o;
    }
}

// ---------------------------------------------------------------------------
// LN2 + @W1 + b1 + GELU; reads xrt (b,c,n), writes z1t (b, m, n)
// ---------------------------------------------------------------------------
__global__ void __launch_bounds__(256) k_mlp1(
    const float* __restrict__ xrt, const float* __restrict__ g2, const float* __restrict__ b2v,
    const float* __restrict__ W1, const float* __restrict__ b1m,
    float* __restrict__ z1t) {
    __shared__ __align__(16) float xt[NC][68];
    __shared__ __align__(16) float wch[32][NMLP];
    __shared__ float meanl[64], rstdl[64];
    __shared__ float gl[NC], bl[NC];
    int b = blockIdx.y; int n0 = blockIdx.x*64; int tid = threadIdx.x;
    if (tid < NC) { gl[tid] = g2[tid]; bl[tid] = b2v[tid]; }
    for (int i = tid; i < NC*64; i += 256) {
        int c = i >> 6, n = i & 63;
        xt[c][n] = xrt[((size_t)b*NC + c)*NN + n0 + n];
    }
    __syncthreads();
    int lane = tid & 63, w = tid >> 6;
    for (int tk = 0; tk < 16; ++tk) {
        int tok = w*16 + tk;
        float a  = xt[lane][tok];
        float bb = (lane < 32) ? xt[64+lane][tok] : 0.f;
        float s = a + bb, sq = a*a + bb*bb;
#pragma unroll
        for (int off = 32; off > 0; off >>= 1) {
            s  += __shfl_xor(s, off);
            sq += __shfl_xor(sq, off);
        }
        if (lane == 0) {
            float mean = s * (1.0f/NC);
            float var  = sq * (1.0f/NC) - mean*mean;
            meanl[tok] = mean; rstdl[tok] = rsqrtf(var + 1e-5f);
        }
    }
    __syncthreads();
    for (int i = tid; i < NC*64; i += 256) {
        int c = i >> 6, n = i & 63;
        xt[c][n] = (xt[c][n]-meanl[n])*rstdl[n]*gl[c]+bl[c];
    }
    int nx = tid & 15, my = tid >> 4;  // n = nx*4, m = my*12
    float acc[4][12];
#pragma unroll
    for (int i = 0; i < 4; ++i)
#pragma unroll
        for (int j = 0; j < 12; ++j) acc[i][j] = 0.f;
    for (int kc = 0; kc < NC; kc += 32) {
        __syncthreads();
        for (int i = tid; i < 32*NMLP; i += 256) {
            int kk = i / NMLP, c = i % NMLP;
            wch[kk][c] = W1[(kc+kk)*NMLP + c];
        }
        __syncthreads();
        for (int kk = 0; kk < 32; ++kk) {
            f4 a0 = *(const f4*)&xt[kc+kk][nx*4];
            float a[4] = {a0.x,a0.y,a0.z,a0.w};
            f4 w0 = *(const f4*)&wch[kk][my*12];
            f4 w1 = *(const f4*)&wch[kk][my*12+4];
            f4 w2 = *(const f4*)&wch[kk][my*12+8];
            float bb[12] = {w0.x,w0.y,w0.z,w0.w,w1.x,w1.y,w1.z,w1.w,w2.x,w2.y,w2.z,w2.w};
#pragma unroll
            for (int i = 0; i < 4; ++i)
#pragma unroll
                for (int j = 0; j < 12; ++j) acc[i][j] += a[i]*bb[j];
        }
    }
#pragma unroll
    for (int j = 0; j < 12; ++j) {
        int mm = my*12 + j;
        float bias = b1m[mm];
        size_t off = ((size_t)b*NMLP + mm)*NN + n0 + nx*4;
        f4 o = { gelu_f(acc[0][j]+bias), gelu_f(acc[1][j]+bias),
                 gelu_f(acc[2][j]+bias), gelu_f(acc[3][j]+bias) };
        *(f4*)&z1t[off] = o;
    }
}

// ---------------------------------------------------------------------------
// Depthwise 5x5x5 conv (pad 2) + GELU + add z1; z2t (b,m,n), register-blocked
// ---------------------------------------------------------------------------
__global__ void __launch_bounds__(256) k_dwconv(
    const float* __restrict__ z1t, const float* __restrict__ Wdw, const float* __restrict__ bdw,
    float* __restrict__ z2t) {
    __shared__ __align__(16) float tin[ND][20][72];
    __shared__ float wl[128];
    int ht = blockIdx.x, mch = blockIdx.y, b = blockIdx.z;
    int h0 = ht*16; int tid = threadIdx.x;
    if (tid < 125) wl[tid] = Wdw[mch*125 + tid];
    const float* src = &z1t[((size_t)b*NMLP + mch)*NN];
    for (int i = tid; i < ND*20*68; i += 256) {
        int dd = i / (20*68); int r = i % (20*68); int hh = r / 68; int ww = r % 68;
        int gh = h0 + hh - 2, gw = ww - 2;
        float v = 0.f;
        if ((unsigned)gh < 64u && (unsigned)gw < 64u) v = src[dd*4096 + gh*64 + gw];
        tin[dd][hh][ww] = v;
    }
    __syncthreads();
    int rowid = tid >> 1; int od = rowid >> 4; int ohl = rowid & 15; int wb = (tid & 1)*32;
    float acc[32];
#pragma unroll
    for (int o = 0; o < 32; ++o) acc[o] = 0.f;
    for (int kd = 0; kd < 5; ++kd) {
        int id = od + kd - 2;
        if ((unsigned)id >= (unsigned)ND) continue;
#pragma unroll
        for (int kh = 0; kh < 5; ++kh) {
            const float* rp = &tin[id][ohl+kh][wb];
            float seg[36];
#pragma unroll
            for (int i = 0; i < 9; ++i) *(f4*)&seg[i*4] = *(const f4*)&rp[i*4];
#pragma unroll
            for (int kw = 0; kw < 5; ++kw) {
                float wt = wl[kd*25 + kh*5 + kw];
#pragma unroll
                for (int o = 0; o < 32; ++o) acc[o] += seg[o+kw]*wt;
            }
        }
    }
    float bias = bdw[mch];
    float* dst = &z2t[((size_t)b*NMLP + mch)*NN + od*4096 + (size_t)(h0+ohl)*64 + wb];
    const float* ctr = &tin[od][ohl+2][wb+2];
#pragma unroll
    for (int o4 = 0; o4 < 32; o4 += 4) {
        f4 ov = { ctr[o4+0] + gelu_f(acc[o4+0]+bias),
                  ctr[o4+1] + gelu_f(acc[o4+1]+bias),
                  ctr[o4+2] + gelu_f(acc[o4+2]+bias),
                  ctr[o4+3] + gelu_f(acc[o4+3]+bias) };
        *(f4*)&dst[o4] = ov;
    }
}

// ---------------------------------------------------------------------------
// Final: out(b,c,n) = z2 @ W2 + b2 + xrt ; 128-token tile, thread = 8n x 6c
// ---------------------------------------------------------------------------
__global__ void __launch_bounds__(256) k_final(
    const float* __restrict__ z2t, const float* __restrict__ W2, const float* __restrict__ b2m,
    const float* __restrict__ xrt, float* __restrict__ out) {
    __shared__ __align__(16) float zch[32][132];
    __shared__ __align__(16) float wch[32][NC];
    int b = blockIdx.y; int n0 = blockIdx.x*128; int tid = threadIdx.x;
    int nx = tid & 15, cy = tid >> 4;   // n = nx*8, c = cy*6
    float acc[8][6];
#pragma unroll
    for (int i = 0; i < 8; ++i)
#pragma unroll
        for (int j = 0; j < 6; ++j) acc[i][j] = 0.f;
    for (int kc = 0; kc < NMLP; kc += 32) {
        __syncthreads();
        for (int i = tid; i < 32*128; i += 256) {
            int kk = i >> 7, n = i & 127;
            zch[kk][n] = z2t[((size_t)b*NMLP + kc + kk)*NN + n0 + n];
        }
        for (int i = tid; i < 32*NC; i += 256) {
            int kk = i / NC, c = i % NC;
            wch[kk][c] = W2[(kc+kk)*NC + c];
        }
        __syncthreads();
        for (int kk = 0; kk < 32; ++kk) {
            f4 a0 = *(const f4*)&zch[kk][nx*8];
            f4 a1 = *(const f4*)&zch[kk][nx*8+4];
            float a[8] = {a0.x,a0.y,a0.z,a0.w,a1.x,a1.y,a1.z,a1.w};
            float2 w0 = *(const float2*)&wch[kk][cy*6];
            float2 w1 = *(const float2*)&wch[kk][cy*6+2];
            float2 w2 = *(const float2*)&wch[kk][cy*6+4];
            float bb[6] = {w0.x,w0.y,w1.x,w1.y,w2.x,w2.y};
#pragma unroll
            for (int i = 0; i < 8; ++i)
#pragma unroll
                for (int j = 0; j < 6; ++j) acc[i][j] += a[i]*bb[j];
        }
    }
#pragma unroll
    for (int j = 0; j < 6; ++j) {
        int c = cy*6 + j;
        float bias = b2m[c];
        size_t off = ((size_t)b*NC + c)*NN + n0 + nx*8;
        f4 x0 = *(const f4*)&xrt[off];
        f4 x1 = *(const f4*)&xrt[off+4];
        f4 o0 = {acc[0][j]+bias+x0.x, acc[1][j]+bias+x0.y, acc[2][j]+bias+x0.z, acc[3][j]+bias+x0.w};
        f4 o1 = {acc[4][j]+bias+x1.x, acc[5][j]+bias+x1.y, acc[6][j]+bias+x1.z, acc[7][j]+bias+x1.w};
        *(f4*)&out[off]   = o0;
        *(f4*)&out[off+4] = o1;
    }
}

// ---------------------------------------------------------------------------
extern "C" void kernel_launch(void* const* d_in, const int* in_sizes, int n_in,
                              void* d_out, int out_size, void* d_ws, size_t ws_size,
                              hipStream_t stream) {
    (void)in_sizes; (void)n_in; (void)out_size; (void)ws_size;
    const float* x     = (const float*)d_in[0];
    const float* means = (const float*)d_in[1];
    const float* ln1_g = (const float*)d_in[2];
    const float* ln1_b = (const float*)d_in[3];
    const float* Wkg   = (const float*)d_in[4];
    const float* Wvg   = (const float*)d_in[5];
    const float* Wq    = (const float*)d_in[6];
    const float* Wk    = (const float*)d_in[7];
    const float* Wv    = (const float*)d_in[8];
    const float* Wproj = (const float*)d_in[9];
    const float* Wconv = (const float*)d_in[10];
    const float* ln2_g = (const float*)d_in[11];
    const float* ln2_b = (const float*)d_in[12];
    const float* W1    = (const float*)d_in[13];
    const float* b1    = (const float*)d_in[14];
    const float* Wdw   = (const float*)d_in[15];
    const float* bdw   = (const float*)d_in[16];
    const float* W2    = (const float*)d_in[17];
    const float* b2    = (const float*)d_in[18];
    float* out = (float*)d_out;

    float* ws = (float*)d_ws;
    const size_t SZ = (size_t)NB*NN*NC;
    float* xn   = ws;
    float* qs   = ws + SZ;
    float* ks   = ws + 2*SZ;
    float* vs   = ws + 3*SZ;
    float* attn = ws + 4*SZ;
    float* xrt  = ws;          // reuse xn (dead after k_qkv)
    float* z1t  = ws + SZ;     // reuse qs,ks (dead after k_attn)
    float* z2t  = ws + 3*SZ;   // reuse vs,attn
    float* faux = ws + 5*SZ;
    float* mnn  = faux;            // 768
    float* gdot = faux + 768;      // 8
    float* bdot = faux + 776;      // 8
    float* kg   = faux + 784;      // 768
    float* vg   = faux + 1552;     // 768
    float* wpc  = faux + 2320;     // 9216 -> ends at 11536
    int* iaux   = (int*)(faux + 11536);
    int* belong = iaux;                  // NB*NN
    int* idx    = iaux + NB*NN;          // NB*NN
    int* inv    = iaux + 2*NB*NN;        // NB*NN
    int* hist   = iaux + 3*NB*NN;        // NB*128*8
    int* baseb  = hist + NB*128*NTOK;    // NB*128*8

    k_precompute<<<dim3(5), dim3(256), 0, stream>>>(
        means, ln1_g, ln1_b, Wkg, Wvg, Wproj, Wconv, mnn, gdot, bdot, kg, vg, wpc);
    k_ln1<<<dim3(NN/64, NB), dim3(256), 0, stream>>>(
        x, ln1_g, ln1_b, mnn, gdot, bdot, xn, belong);
    k_hist<<<dim3(NN/256, NB), dim3(256), 0, stream>>>(belong, hist);
    k_scan<<<dim3(NB), dim3(256), 0, stream>>>(hist, baseb);
    k_scatteridx<<<dim3(NN/256, NB), dim3(256), 0, stream>>>(belong, baseb, idx, inv);
    k_qkv<<<dim3(NN/128, NB), dim3(256), 0, stream>>>(xn, idx, Wq, Wk, Wv, qs, ks, vs);
    k_attn<<<dim3(NGRP, NHEADS, NB), dim3(256), 0, stream>>>(qs, ks, vs, kg, vg, attn);
    k_scatproj<<<dim3(NN/64, NB), dim3(256), 0, stream>>>(attn, inv, wpc, x, xrt);
    k_mlp1<<<dim3(NN/64, NB), dim3(256), 0, stream>>>(xrt, ln2_g, ln2_b, W1, b1, z1t);
    k_dwconv<<<dim3(4, NMLP, NB), dim3(256), 0, stream>>>(z1t, Wdw, bdw, z2t);
    k_final<<<dim3(NN/128, NB), dim3(256), 0, stream>>>(z2t, W2, b2, xrt, out);
}